// Round 1
// baseline (131.219 us; speedup 1.0000x reference)
//
#include <hip/hip_runtime.h>

// Closed-form: all 10 segment steps are exp(-i*phi_s*H) with the SAME
// traceless Hermitian 2x2 H, so the product is exp(-i*(sum phi)*H).
// infidelity_b = 1 - (cr * sin(DT*S_b*r) / r)^2,  S_b = sum_s omega[b,s]
// loss = mean((infid_data - infidelity)^2)

#define ND 2000000
#define NS 10
#define DTC 0.1f

__global__ __launch_bounds__(256) void loss_kernel(
    const float* __restrict__ para,
    const float* __restrict__ omega,
    const float* __restrict__ infid,
    float* __restrict__ out) {

    // Scalar precompute (broadcast loads, cached)
    const float x00 = para[0], x01 = para[1], x10 = para[2], x11 = para[3];
    const float a  = 0.5f * (x00 - x11);
    const float cr = 0.5f + 0.5f * (x01 + x10);
    const float ci = 0.5f * (x01 - x10);
    const float rsq = a * a + cr * cr + ci * ci;
    const float r = sqrtf(rsq);
    const float cr_over_r = cr / r;
    const float dt_r = DTC * r;

    const int tid = blockIdx.x * blockDim.x + threadIdx.x;
    const int b0 = tid * 4;          // 4 batch items per thread
    float acc = 0.0f;

    if (b0 < ND) {                   // ND % 4 == 0, so whole group is valid
        // 40 contiguous floats = 10 float4 loads, 160B-aligned (b0 % 4 == 0)
        const float4* om4 = (const float4*)(omega + (size_t)b0 * NS);
        float s[4] = {0.f, 0.f, 0.f, 0.f};
        #pragma unroll
        for (int k = 0; k < 10; ++k) {
            float4 v = om4[k];
            s[(4 * k + 0) / 10] += v.x;
            s[(4 * k + 1) / 10] += v.y;
            s[(4 * k + 2) / 10] += v.z;
            s[(4 * k + 3) / 10] += v.w;
        }
        const float4 fi4 = *(const float4*)(infid + b0);
        const float fi[4] = {fi4.x, fi4.y, fi4.z, fi4.w};
        #pragma unroll
        for (int j = 0; j < 4; ++j) {
            float theta = dt_r * s[j];
            float t = cr_over_r * __sinf(theta) ;
            // use precise sinf for safety against the np reference:
            t = cr_over_r * sinf(theta);
            float infidelity = 1.0f - t * t;
            float d = fi[j] - infidelity;
            acc += d * d;
        }
    }

    // wave (64-lane) shuffle reduction
    #pragma unroll
    for (int off = 32; off > 0; off >>= 1)
        acc += __shfl_down(acc, off, 64);

    __shared__ float wsum[4];        // 256 threads = 4 waves
    const int lane = threadIdx.x & 63;
    const int wid  = threadIdx.x >> 6;
    if (lane == 0) wsum[wid] = acc;
    __syncthreads();
    if (threadIdx.x == 0) {
        float t = wsum[0] + wsum[1] + wsum[2] + wsum[3];
        atomicAdd(out, t * (1.0f / (float)ND));
    }
}

extern "C" void kernel_launch(void* const* d_in, const int* in_sizes, int n_in,
                              void* d_out, int out_size, void* d_ws, size_t ws_size,
                              hipStream_t stream) {
    const float* para  = (const float*)d_in[0];   // (2,2)
    const float* omega = (const float*)d_in[1];   // (2M, 10)
    const float* infid = (const float*)d_in[2];   // (2M,)
    float* out = (float*)d_out;

    hipMemsetAsync(out, 0, sizeof(float), stream);  // d_out is poisoned 0xAA

    const int groups = ND / 4;                      // 500,000
    const int block = 256;
    const int grid = (groups + block - 1) / block;  // 1954
    loss_kernel<<<grid, block, 0, stream>>>(para, omega, infid, out);
}